// Round 6
// baseline (56.050 us; speedup 1.0000x reference)
//
#include <hip/hip_runtime.h>

#define BMOL 256

// ragged sizes are static in the reference: n_b = 64 + (b % 129)
__device__ __forceinline__ int mol_n(int b) { return 64 + (b % 129); }
// prefix-sum offset of molecule b (one full cycle of 129 sums to 16512)
__device__ __forceinline__ int mol_off(int b) {
  int full = b / 129, rem = b % 129;
  return full * 16512 + 64 * rem + (rem * (rem - 1)) / 2;
}

__device__ __forceinline__ float frcp(float x) { return __builtin_amdgcn_rcpf(x); }

__global__ void zero_acc(float* acc) { acc[threadIdx.x] = 0.0f; }

// One WAVE per (molecule, upper-tri 64x64 tile pair, 8-row i-octet).
// lane <-> j. A = P[i][j] is lane-coalesced. C = P[j][i0..i0+7] is LANE-PRIVATE
// CONTIGUOUS (96 B, 16B-aligned) -> 6 dwordx4, no transpose, no LDS, no barrier.
// Each unordered pair computed once (both orderings' terms from A,C).
__global__ __launch_bounds__(256, 4) void pair_units(const float* __restrict__ pf,
                                                     const float* __restrict__ pos,
                                                     float* __restrict__ acc) {
  const int wave = threadIdx.x >> 6;
  const int lane = threadIdx.x & 63;
  const int u = blockIdx.x * 4 + wave;          // 12288 wave-units = 256 mol x 48
  const int b = u / 48;
  const int rest = u - b * 48;
  const int t = rest >> 3;                      // tile pair 0..5 (upper tri of 3x3)
  const int k = rest & 7;                       // i-octet within ti tile
  const int ti = (0x210100 >> (4 * t)) & 0xF;   // {0,0,1,0,1,2}[t]
  const int tj = (0x222110 >> (4 * t)) & 0xF;   // {0,1,1,2,2,2}[t]
  const int n = mol_n(b);
  const int j0 = tj * 64;
  const int i0 = ti * 64 + k * 8;
  if (j0 >= n || i0 >= n) return;               // dead wave: uniform cheap exit

  const int off = mol_off(b);
  const int j = j0 + lane;
  const bool jv = (j < n);

  // C = P[j][i0..i0+7]: per-lane contiguous 24 floats, 16B-aligned -> 6 x float4
  float C[24];
  {
    const float4* cp = reinterpret_cast<const float4*>(
        pf + (size_t)(off + j) * 576 + (size_t)i0 * 3);
#pragma unroll
    for (int q = 0; q < 6; ++q) {
      float4 v = jv ? cp[q] : float4{0.f, 0.f, 0.f, 0.f};
      C[4 * q + 0] = v.x; C[4 * q + 1] = v.y;
      C[4 * q + 2] = v.z; C[4 * q + 3] = v.w;
    }
  }

  // A = P[i0+kk][j] (lane-coalesced) and pos_i (wave-uniform)
  float Ax[8], Ay[8], Az[8], Pix[8], Piy[8], Piz[8];
#pragma unroll
  for (int kk = 0; kk < 8; ++kk) {
    const int i = i0 + kk;
    const bool iv = (i < n);
    float ax = 0.f, ay = 0.f, az = 0.f, px = 0.f, py = 0.f, pz = 0.f;
    if (iv && jv) {
      const float* ap = pf + (size_t)(off + i) * 576 + 3 * j;
      ax = ap[0]; ay = ap[1]; az = ap[2];
    }
    if (iv) {
      const float* pp = pos + (size_t)(off + i) * 3;
      px = pp[0]; py = pp[1]; pz = pp[2];
    }
    Ax[kk] = ax; Ay[kk] = ay; Az[kk] = az;
    Pix[kk] = px; Piy[kk] = py; Piz[kk] = pz;
  }
  float pjx = 0.f, pjy = 0.f, pjz = 0.f;
  if (jv) {
    const float* pp = pos + (size_t)(off + j) * 3;
    pjx = pp[0]; pjy = pp[1]; pjz = pp[2];
  }

  const float nf  = (float)n;
  const float sc1 = (nf - 1.f) / (nf * nf);
  const float sc2 = 1.f / nf;
  float accv = 0.f;

#pragma unroll
  for (int kk = 0; kk < 8; ++kk) {
    const int i = i0 + kk;
    if (i < n) {  // wave-uniform
      const float ax = Ax[kk], ay = Ay[kk], az = Az[kk];
      const float cx = C[3 * kk + 0], cy = C[3 * kk + 1], cz = C[3 * kk + 2];
      if (jv && j > i) {  // strict upper triangle: each unordered pair once
        const float rx = Pix[kk] - pjx, ry = Piy[kk] - pjy, rz = Piz[kk] - pjz;
        const float d2 = rx * rx + ry * ry + rz * rz;
        const float D  = (d2 > 0.f) ? __builtin_amdgcn_sqrtf(d2) : 0.f;
        const float pn2 = ax * ax + ay * ay + az * az;
        const float Pn  = (pn2 > 0.f) ? __builtin_amdgcn_sqrtf(pn2) : 0.f;
        const float qn2 = cx * cx + cy * cy + cz * cz;
        const float Qn  = (qn2 > 0.f) ? __builtin_amdgcn_sqrtf(qn2) : 0.f;
        const float invDeps = frcp(D + 1e-3f);

        // term1 (symmetric): 2 * cos(P_ij,P_ji)/(D+1e-3)
        const float dot_pp = ax * cx + ay * cy + az * cz;
        const float t1 = 2.f * dot_pp * frcp(fmaxf(Pn * Qn, 1e-18f)) * invDeps;
        // term2 (symmetric): 2 * (Pn-Qn)^2
        const float dpn = Pn - Qn;
        const float t2 = 2.f * dpn * dpn;
        // term3 (both orderings): |cos(P_ij,r)| + |cos(P_ji,-r)|, each /(D+1e-3)
        const float dot_ar = ax * rx + ay * ry + az * rz;
        const float dot_cr = cx * rx + cy * ry + cz * rz;
        const float t3 = (fabsf(dot_ar) * frcp(fmaxf(Pn * D, 1e-18f)) +
                          fabsf(dot_cr) * frcp(fmaxf(Qn * D, 1e-18f))) * invDeps;
        accv += sc1 * t1 + sc2 * (t2 - t3);
      }
      if (jv && j == i) {
        // diagonal of term1: cos = pn2/max(pn2,eps), D=0 -> /1e-3
        const float pn2 = ax * ax + ay * ay + az * az;
        accv += sc1 * (pn2 * frcp(fmaxf(pn2, 1e-18f))) * 1000.f;
      }
    }
  }

  // wave-64 reduce, one atomic per wave
  for (int o = 32; o > 0; o >>= 1) accv += __shfl_xor(accv, o, 64);
  if (lane == 0) atomicAdd(&acc[b], accv);
}

__global__ void finalize(const float* __restrict__ acc, float* __restrict__ out) {
  __shared__ float red[4];
  const int lane = threadIdx.x & 63, wave = threadIdx.x >> 6;
  float v = acc[threadIdx.x];
  for (int o = 32; o > 0; o >>= 1) v += __shfl_xor(v, o, 64);
  if (lane == 0) red[wave] = v;
  __syncthreads();
  if (threadIdx.x == 0)
    out[0] = (red[0] + red[1] + red[2] + red[3]) * (1.0f / (float)BMOL);
}

extern "C" void kernel_launch(void* const* d_in, const int* in_sizes, int n_in,
                              void* d_out, int out_size, void* d_ws, size_t ws_size,
                              hipStream_t stream) {
  const float* pf  = (const float*)d_in[0];   // (TOTAL, 192, 3) f32
  const float* pos = (const float*)d_in[1];   // (TOTAL, 3) f32
  float* acc = (float*)d_ws;                  // [256] per-molecule accumulators
  float* out = (float*)d_out;

  hipLaunchKernelGGL(zero_acc, dim3(1), dim3(BMOL), 0, stream, acc);
  hipLaunchKernelGGL(pair_units, dim3(BMOL * 48 / 4), dim3(256), 0, stream, pf, pos, acc);
  hipLaunchKernelGGL(finalize, dim3(1), dim3(BMOL), 0, stream, acc, out);
}